// Round 7
// baseline (891.529 us; speedup 1.0000x reference)
//
#include <hip/hip_runtime.h>
#include <hip/hip_fp16.h>
#include <math.h>

#define NB    2
#define NQ    8192
#define NCIN  256
#define NG    4
#define NP    8
#define NGP   32
#define NCIMG 32
#define NCOUT 128
#define NVIEW 6
#define GXD   64
#define GYD   64
#define GZD   4

typedef float f32x4 __attribute__((ext_vector_type(4)));
typedef short s16x8 __attribute__((ext_vector_type(8)));
typedef unsigned short u16;
typedef unsigned int   u32;

__device__ __forceinline__ u16 bf16_rne(float f) {
    u32 u = __float_as_uint(f);
    u32 r = (u + 0x7FFFu + ((u >> 16) & 1u)) >> 16;
    return (u16)r;
}
__device__ __forceinline__ float bf16_f(u16 h) {
    return __uint_as_float(((u32)h) << 16);
}

// ---------------------------------------------------------------------------
// feature transpose: [B,N,128,H,W] -> [B,G,N,H,W,32]
// ---------------------------------------------------------------------------
__global__ void transpose_feat(const float* __restrict__ src, float* __restrict__ dst,
                               int H, int W)
{
    const int total = NB * NG * NVIEW * H * W * 32;
    for (int i = blockIdx.x * blockDim.x + threadIdx.x; i < total;
         i += gridDim.x * blockDim.x) {
        int c = i & 31;
        int r = i >> 5;
        int x = r % W;  r /= W;
        int y = r % H;  r /= H;
        int n = r % NVIEW; r /= NVIEW;
        int g = r & 3;  r >>= 2;
        int b = r;
        dst[i] = src[(((size_t)(b * NVIEW + n) * 128 + g * 32 + c) * H + y) * W + x];
    }
}

// pts_bev [B,256,64,64] -> channel-last [B,64*64,256] (tiled transpose)
__global__ __launch_bounds__(256) void transpose_pts(const float* __restrict__ src,
                                                     float* __restrict__ dst)
{
    __shared__ float tile[64][65];
    const int tid = blockIdx.x;
    const int b = tid >> 8, rest = tid & 255;
    const int p0 = (rest >> 2) << 6, c0 = (rest & 3) << 6;
    const int t = threadIdx.x;
    for (int i = t; i < 4096; i += 256) {
        const int c = i >> 6, p = i & 63;
        tile[c][p] = src[((size_t)(b * 256 + c0 + c) << 12) + p0 + p];
    }
    __syncthreads();
    for (int i = t; i < 4096; i += 256) {
        const int p = i >> 6, c = i & 63;
        dst[((size_t)(b * 4096) + p0 + p) * 256 + c0 + c] = tile[c][p];
    }
}

// wT[col][k]: col<96 -> w_off col, else w_sc col-96
__global__ void pack_wT(const float* __restrict__ w_off, const float* __restrict__ w_sc,
                        float* __restrict__ wT)
{
    int i = blockIdx.x * 256 + threadIdx.x;
    if (i >= 224 * 256) return;
    int col = i >> 8, k = i & 255;
    wT[i] = (col < 96) ? w_off[k * 96 + col] : w_sc[k * 128 + (col - 96)];
}

// w_agg [1024][128] fp32 -> bf16 [co][k]
__global__ void pack_wagT(const float* __restrict__ w_agg, u16* __restrict__ dst)
{
    int i = blockIdx.x * 256 + threadIdx.x;
    if (i >= 128 * 1024) return;
    int co = i >> 10, k = i & 1023;
    dst[i] = bf16_rne(w_agg[k * 128 + co]);
}

// conv weight pack: [CO][CI][3][3] fp32 -> hi/lo bf16 [tap9][CO][CI]
__global__ void pack_conv_w(const float* __restrict__ src, u16* __restrict__ hi,
                            u16* __restrict__ lo, int CI, int CO)
{
    const int N = CO * CI * 9;
    for (int i = blockIdx.x * blockDim.x + threadIdx.x; i < N;
         i += gridDim.x * blockDim.x) {
        int tap = i % 9;
        int r = i / 9;
        int ci = r % CI;
        int co = r / CI;
        float v = src[i];
        u16 h = bf16_rne(v);
        size_t d = ((size_t)tap * CO + co) * CI + ci;
        hi[d] = h;
        lo[d] = bf16_rne(v - bf16_f(h));
    }
}

// x0 fp32 (atomic-accumulated) -> bf16 hi/lo planes
__global__ void split_x0(const float* __restrict__ x, u16* __restrict__ h,
                         u16* __restrict__ lo)
{
    const int N = NB * 4096 * 512;
    for (int i = blockIdx.x * blockDim.x + threadIdx.x; i < N;
         i += gridDim.x * blockDim.x) {
        float v = x[i];
        u16 hh = bf16_rne(v);
        h[i] = hh;
        lo[i] = bf16_rne(v - bf16_f(hh));
    }
}

// ---------------------------------------------------------------------------
// fused per-query kernel, 8 queries per block, 256 threads.
// gather -> offset/scale matmul -> tap precompute -> coalesced sampling ->
// split-bf16 MFMA agg (M=8 via zero-row lanes) -> atomic CL scatter.
// ---------------------------------------------------------------------------
__global__ __launch_bounds__(256) void fused_query8(
    const float* __restrict__ pts_cl, const float* __restrict__ l2i,
    const float* __restrict__ qmask,
    const float* __restrict__ wT, const float* __restrict__ b_off,
    const float* __restrict__ b_sc,
    const u16* __restrict__ wagT, const float* __restrict__ b_agg,
    const int* __restrict__ vxp, const int* __restrict__ vyp, const int* __restrict__ vzp,
    const float* __restrict__ fT,
    float* __restrict__ xout_cl)
{
    const int q0 = blockIdx.x << 3;
    const int b  = q0 >> 13;
    const int t  = threadIdx.x;

    __shared__ float s_pts[8][256];
    __shared__ float s_off[8][96];
    __shared__ float s_sw[8][128];
    __shared__ float s_l2i[96];
    __shared__ u32   s_toff[256][16];
    __shared__ u16   s_twgt[256][16];
    __shared__ __align__(16) u16 s_fh[8][1024];
    __shared__ __align__(16) u16 s_fl[8][1024];
    __shared__ int   s_vx[8], s_vy[8], s_vz[8];
    __shared__ float s_qm[8];

    if (t < 8) {
        s_vx[t] = vxp[q0 + t]; s_vy[t] = vyp[q0 + t]; s_vz[t] = vzp[q0 + t];
        s_qm[t] = qmask[q0 + t];
    }
    if (t < 96) s_l2i[t] = l2i[b * 96 + t];
    __syncthreads();

    // coalesced gather of 8 query features (channel-last pts)
    #pragma unroll
    for (int q = 0; q < 8; ++q)
        s_pts[q][t] = pts_cl[((size_t)(b * 4096) + s_vy[q] * 64 + s_vx[q]) * 256 + t];
    __syncthreads();

    // offset (96) + scale-logit (128) matmuls, one column/thread, 8-q amortized
    if (t < 224) {
        const float* __restrict__ wrow = wT + t * 256;
        const float bias = (t < 96) ? b_off[t] : b_sc[t - 96];
        float a0 = bias, a1 = bias, a2 = bias, a3 = bias;
        float a4 = bias, a5 = bias, a6 = bias, a7 = bias;
        #pragma unroll 4
        for (int k = 0; k < 256; ++k) {
            const float wk = wrow[k];
            a0 = fmaf(s_pts[0][k], wk, a0); a1 = fmaf(s_pts[1][k], wk, a1);
            a2 = fmaf(s_pts[2][k], wk, a2); a3 = fmaf(s_pts[3][k], wk, a3);
            a4 = fmaf(s_pts[4][k], wk, a4); a5 = fmaf(s_pts[5][k], wk, a5);
            a6 = fmaf(s_pts[6][k], wk, a6); a7 = fmaf(s_pts[7][k], wk, a7);
        }
        if (t < 96) {
            s_off[0][t] = a0; s_off[1][t] = a1; s_off[2][t] = a2; s_off[3][t] = a3;
            s_off[4][t] = a4; s_off[5][t] = a5; s_off[6][t] = a6; s_off[7][t] = a7;
        } else {
            const int c = t - 96;
            s_sw[0][c] = a0; s_sw[1][c] = a1; s_sw[2][c] = a2; s_sw[3][c] = a3;
            s_sw[4][c] = a4; s_sw[5][c] = a5; s_sw[6][c] = a6; s_sw[7][c] = a7;
        }
    }
    __syncthreads();

    // one thread per (q,gp): softmax + projection + view select + 16 taps
    {
        const int q = t >> 5, gp = t & 31;
        float a0 = s_sw[q][gp * 4 + 0], a1 = s_sw[q][gp * 4 + 1];
        float a2 = s_sw[q][gp * 4 + 2], a3 = s_sw[q][gp * 4 + 3];
        float m  = fmaxf(fmaxf(a0, a1), fmaxf(a2, a3));
        float e0 = expf(a0 - m), e1 = expf(a1 - m), e2 = expf(a2 - m), e3 = expf(a3 - m);
        float inv = 1.f / (e0 + e1 + e2 + e3);
        const float sw0 = e0 * inv, sw1 = e1 * inv, sw2 = e2 * inv, sw3 = e3 * inv;

        float cx = ((float)s_vx[q] + 0.5f) * 0.6f - 19.2f;
        float cy = ((float)s_vy[q] + 0.5f) * 0.6f - 19.2f;
        float cz = ((float)s_vz[q] + 0.5f) * 0.4f - 1.0f;
        float sx = cx + s_off[q][gp * 3 + 0] * 0.6f;
        float sy = cy + s_off[q][gp * 3 + 1] * 0.6f;
        float sz = cz + s_off[q][gp * 3 + 2] * 0.4f;

        int best = 0; float bu = 0.f, bv = 0.f; bool found = false;
        #pragma unroll
        for (int n = 0; n < NVIEW; ++n) {
            const float* M = &s_l2i[n * 16];
            float px = M[0] * sx + M[1] * sy + M[2]  * sz + M[3];
            float py = M[4] * sx + M[5] * sy + M[6]  * sz + M[7];
            float pz = M[8] * sx + M[9] * sy + M[10] * sz + M[11];
            float homo = fmaxf(pz, 1e-5f);
            float u = px / homo / 704.0f;
            float v = py / homo / 256.0f;
            bool val = (pz > 1e-5f) && (u > 0.f) && (u < 1.f) && (v > 0.f) && (v < 1.f);
            if (n == 0) { bu = u; bv = v; }
            if (val && !found) { found = true; best = n; bu = u; bv = v; }
        }

        const int g = gp >> 3;
        const u32 bgv = (u32)((b * 4 + g) * 6 + best);
        auto tapgen = [&](int lidx, int W, int H, u32 lbase, float swl) {
            float px = fminf(fmaxf(bu * (float)W - 0.5f, -1.0e8f), 1.0e8f);
            float py = fminf(fmaxf(bv * (float)H - 0.5f, -1.0e8f), 1.0e8f);
            float x0f = floorf(px), y0f = floorf(py);
            float wx = px - x0f, wy = py - y0f;
            int x0 = (int)x0f, y0 = (int)y0f;
            const u32 base = lbase + bgv * (u32)(H * W * 32);
            #pragma unroll
            for (int ti = 0; ti < 4; ++ti) {
                int xi = x0 + (ti & 1), yi = y0 + (ti >> 1);
                float bw = ((ti & 1) ? wx : 1.f - wx) * ((ti >> 1) ? wy : 1.f - wy);
                bool ok = ((unsigned)xi < (unsigned)W) && ((unsigned)yi < (unsigned)H);
                u32 off = ok ? (base + ((u32)(yi * W + xi) << 5)) : 0u;
                float wgt = ok ? swl * bw : 0.f;
                s_toff[t][lidx * 4 + ti] = off;
                s_twgt[t][lidx * 4 + ti] = __half_as_ushort(__float2half(wgt));
            }
        };
        tapgen(0, 88, 32, 0u,       sw0);
        tapgen(1, 44, 16, 4325376u, sw1);
        tapgen(2, 22,  8, 5406720u, sw2);
        tapgen(3, 11,  4, 5677056u, sw3);
    }
    __syncthreads();

    // sampling: half-wave shares one (q,gp) -> coalesced 128B gathers
    for (int i = t; i < 8192; i += 256) {
        const int pair = i >> 5, c = i & 31;
        float acc = 0.f;
        #pragma unroll
        for (int tp = 0; tp < 16; ++tp) {
            const u32 off = s_toff[pair][tp];
            const float wgt = __half2float(__ushort_as_half(s_twgt[pair][tp]));
            acc = fmaf(wgt, fT[off + c], acc);
        }
        const int gp = pair & 31, q = pair >> 5;
        const int g = gp >> 3, p = gp & 7;
        const int k = ((p << 2) + g) * 32 + c;
        const u16 h  = bf16_rne(acc);
        const u16 lo = bf16_rne(acc - bf16_f(h));
        const int kk = (((k >> 3) ^ q) << 3) | (k & 7);   // k-block swizzle by q
        s_fh[q][kk] = h;
        s_fl[q][kk] = lo;
    }
    __syncthreads();

    // agg MFMA: M=16 rows, rows 0..7 real (lanes row>=8 feed zero A-frags)
    {
        const int wv = t >> 6, l = t & 63;
        const int l15 = l & 15, kg = l >> 4;    // kg in 0..3
        f32x4 acc0 = {0.f, 0.f, 0.f, 0.f}, acc1 = {0.f, 0.f, 0.f, 0.f};
        const u16* __restrict__ B0 = wagT + (((wv * 2) * 16 + l15) << 10);
        const u16* __restrict__ B1 = wagT + (((wv * 2 + 1) * 16 + l15) << 10);
        const bool realA = (l15 < 8);
        for (int ks = 0; ks < 32; ++ks) {
            s16x8 Ah = {0, 0, 0, 0, 0, 0, 0, 0};
            s16x8 Al = {0, 0, 0, 0, 0, 0, 0, 0};
            if (realA) {
                const int kk = ((((ks << 2) + kg) ^ l15) << 3);
                Ah = *reinterpret_cast<const s16x8*>(&s_fh[l15][kk]);
                Al = *reinterpret_cast<const s16x8*>(&s_fl[l15][kk]);
            }
            const int ko = (ks << 5) + (kg << 3);
            const s16x8 Bh0 = *reinterpret_cast<const s16x8*>(B0 + ko);
            const s16x8 Bh1 = *reinterpret_cast<const s16x8*>(B1 + ko);
            acc0 = __builtin_amdgcn_mfma_f32_16x16x32_bf16(Ah, Bh0, acc0, 0, 0, 0);
            acc0 = __builtin_amdgcn_mfma_f32_16x16x32_bf16(Al, Bh0, acc0, 0, 0, 0);
            acc1 = __builtin_amdgcn_mfma_f32_16x16x32_bf16(Ah, Bh1, acc1, 0, 0, 0);
            acc1 = __builtin_amdgcn_mfma_f32_16x16x32_bf16(Al, Bh1, acc1, 0, 0, 0);
        }
        if (l < 32) {   // C rows 0..7 live in lanes 0..31 (row = kg*4+reg)
            #pragma unroll
            for (int reg = 0; reg < 4; ++reg) {
                const int q = kg * 4 + reg;
                const size_t pbase =
                    ((size_t)(b * 4096) + s_vy[q] * 64 + s_vx[q]) * 512 + s_vz[q];
                const float qm = s_qm[q];
                {
                    const int co = (wv * 2) * 16 + l15;
                    atomicAdd(&xout_cl[pbase + co * 4], (acc0[reg] + b_agg[co]) * qm);
                }
                {
                    const int co = (wv * 2 + 1) * 16 + l15;
                    atomicAdd(&xout_cl[pbase + co * 4], (acc1[reg] + b_agg[co]) * qm);
                }
            }
        }
    }
}

// ---------------------------------------------------------------------------
// 3x3 SAME conv + BN + ReLU, split-bf16 MFMA implicit GEMM.
// Pre-split bf16 hi/lo channel-last input.  Block: ROWS output rows x 64 x x
// (NSUB*32) co; wave (r, ns) owns row r, 32 co (2 n-frags) x 64 px (4 m-frags).
// Epilogue writes bf16 hi/lo CL (or fp32 NCHW for the last layer).
// ---------------------------------------------------------------------------
template<int ROWS, int NSUB, bool LAST>
__global__ __launch_bounds__(64 * ROWS * NSUB) void conv3x3_mfma2(
    const u16* __restrict__ xinh, const u16* __restrict__ xinl,
    const u16* __restrict__ whi, const u16* __restrict__ wlo,
    const float* __restrict__ gam, const float* __restrict__ bet,
    u16* __restrict__ youth, u16* __restrict__ youtl,
    float* __restrict__ ynchw, int CI, int CO)
{
    constexpr int STRIPS = 64 / ROWS;
    constexpr int NTHR = 64 * ROWS * NSUB;
    constexpr int SR = ROWS + 2;
    const int b = blockIdx.x / STRIPS, s = blockIdx.x % STRIPS;
    const int y0 = s * ROWS;
    const int co0 = blockIdx.y * (NSUB * 32);
    const int t = threadIdx.x;
    const int wid = t >> 6, l = t & 63;
    const int l15 = l & 15, kg = l >> 4;
    const int r = wid / NSUB, ns = wid % NSUB;

    __shared__ __align__(16) u16 sh[SR * 66 * 32];
    __shared__ __align__(16) u16 sl[SR * 66 * 32];

    const int coA = co0 + ns * 32 + l15;
    const int coB = coA + 16;

    f32x4 acc[4][2];
    #pragma unroll
    for (int m = 0; m < 4; ++m) {
        acc[m][0] = (f32x4){0.f, 0.f, 0.f, 0.f};
        acc[m][1] = (f32x4){0.f, 0.f, 0.f, 0.f};
    }

    for (int cc = 0; cc < CI; cc += 32) {
        __syncthreads();
        for (int i = t; i < SR * 66 * 4; i += NTHR) {
            const int cb = i & 3, r2 = i >> 2;
            const int xx = r2 % 66, rr = r2 / 66;
            const int yi = y0 - 1 + rr, xi = xx - 1;
            uint4 H = {0, 0, 0, 0}, L = {0, 0, 0, 0};
            if ((unsigned)yi < 64u && (unsigned)xi < 64u) {
                const size_t src = ((size_t)(b * 4096 + yi * 64 + xi)) * CI + cc + cb * 8;
                H = *reinterpret_cast<const uint4*>(xinh + src);
                L = *reinterpret_cast<const uint4*>(xinl + src);
            }
            const int off = (rr * 66 + xx) * 32 + ((cb ^ ((xx ^ (xx >> 2)) & 3)) << 3);
            *reinterpret_cast<uint4*>(&sh[off]) = H;
            *reinterpret_cast<uint4*>(&sl[off]) = L;
        }
        __syncthreads();

        #pragma unroll
        for (int tap = 0; tap < 9; ++tap) {
            const int ky = tap / 3, kx = tap % 3;
            const size_t woA = ((size_t)tap * CO + coA) * CI + cc + kg * 8;
            const size_t woB = ((size_t)tap * CO + coB) * CI + cc + kg * 8;
            const s16x8 BhA = *reinterpret_cast<const s16x8*>(whi + woA);
            const s16x8 BlA = *reinterpret_cast<const s16x8*>(wlo + woA);
            const s16x8 BhB = *reinterpret_cast<const s16x8*>(whi + woB);
            const s16x8 BlB = *reinterpret_cast<const s16x8*>(wlo + woB);
            #pragma unroll
            for (int m = 0; m < 4; ++m) {
                const int xx = m * 16 + l15 + kx;
                const int off = ((r + ky) * 66 + xx) * 32
                              + ((kg ^ ((xx ^ (xx >> 2)) & 3)) << 3);
                const s16x8 Ah = *reinterpret_cast<const s16x8*>(&sh[off]);
                const s16x8 Al = *reinterpret_cast<const s16x8*>(&sl[off]);
                acc[m][0] = __builtin_amdgcn_mfma_f32_16x16x32_bf16(Ah, BhA, acc[m][0], 0, 0, 0);
                acc[m][0] = __builtin_amdgcn_mfma_f32_16x16x32_bf16(Ah, BlA, acc[m][0], 0, 0, 0);
                acc[m][0] = __builtin_amdgcn_mfma_f32_16x16x32_bf16(Al, BhA, acc[m][0], 0, 0, 0);
                acc[m][1] = __builtin_amdgcn_mfma_f32_16x16x32_bf16(Ah, BhB, acc[m][1], 0, 0, 0);
                acc[m][1] = __builtin_amdgcn_mfma_f32_16x16x32_bf16(Ah, BlB, acc[m][1], 0, 0, 0);
                acc[m][1] = __builtin_amdgcn_mfma_f32_16x16x32_bf16(Al, BhB, acc[m][1], 0, 0, 0);
            }
        }
    }

    const float inv = 0.99999500003749978f;   // 1/sqrt(1+1e-5)
    const int row = y0 + r;
    #pragma unroll
    for (int j = 0; j < 2; ++j) {
        const int co = j ? coB : coA;
        const float gsc = gam[co] * inv;
        const float bta = bet[co];
        #pragma unroll
        for (int m = 0; m < 4; ++m) {
            #pragma unroll
            for (int reg = 0; reg < 4; ++reg) {
                const int x = m * 16 + kg * 4 + reg;
                const float val = fmaxf(fmaf(acc[m][j][reg], gsc, bta), 0.f);
                if (LAST) {
                    ynchw[(((size_t)(b * CO + co)) << 12) + row * 64 + x] = val;
                } else {
                    const size_t idx = ((size_t)(b * 4096 + row * 64 + x)) * CO + co;
                    const u16 h = bf16_rne(val);
                    youth[idx] = h;
                    youtl[idx] = bf16_rne(val - bf16_f(h));
                }
            }
        }
    }
}

// ---------------------------------------------------------------------------
extern "C" void kernel_launch(void* const* d_in, const int* in_sizes, int n_in,
                              void* d_out, int out_size, void* d_ws, size_t ws_size,
                              hipStream_t stream)
{
    const float* feat0    = (const float*)d_in[0];
    const float* feat1    = (const float*)d_in[1];
    const float* feat2    = (const float*)d_in[2];
    const float* feat3    = (const float*)d_in[3];
    const float* pts_bev  = (const float*)d_in[4];
    const float* l2i      = (const float*)d_in[5];
    const float* qmask    = (const float*)d_in[6];
    const int*   vox_x    = (const int*)d_in[7];
    const int*   vox_y    = (const int*)d_in[8];
    const int*   vox_z    = (const int*)d_in[9];
    const float* w_off    = (const float*)d_in[10];
    const float* b_off    = (const float*)d_in[11];
    const float* w_sc     = (const float*)d_in[12];
    const float* b_sc     = (const float*)d_in[13];
    const float* w_agg    = (const float*)d_in[14];
    const float* b_agg    = (const float*)d_in[15];
    const float* conv1_w  = (const float*)d_in[16];
    const float* conv2_w  = (const float*)d_in[17];
    const float* conv3_w  = (const float*)d_in[18];
    const float* conv4_w  = (const float*)d_in[19];
    const float* bn1_g    = (const float*)d_in[20];
    const float* bn1_b    = (const float*)d_in[21];
    const float* bn2_g    = (const float*)d_in[22];
    const float* bn2_b    = (const float*)d_in[23];
    const float* bn3_g    = (const float*)d_in[24];
    const float* bn3_b    = (const float*)d_in[25];
    const float* bn4_g    = (const float*)d_in[26];
    const float* bn4_b    = (const float*)d_in[27];

    // ---- workspace layout (bytes), total 64,921,600 (< proven 65,150,976) ----
    // [0, 22978560)            fT0..3 features; reused for packed conv weights
    // [22978560, 39755776)     x0 fp32 (conv1 in, atomic) -> x2 hi/lo
    // [39755776, 48144384)     pts_cl -> x0h -> x3h
    // [48144384, 48635904)     wagT (262144) + wTp (229376)  [live only until
    //                          fused_query8 done; then overwritten by x0l]
    // [48144384, 56532992)     x0l -> x3l (written by split_x0, after wagT dead)
    // [56532992, 64921600)     x1 hi/lo
    char* wsb = (char*)d_ws;
    float* fT0 = (float*)wsb;
    float* fT1 = fT0 + 4325376;
    float* fT2 = fT1 + 1081344;
    float* fT3 = fT2 + 270336;
    u16* wpk = (u16*)wsb;
    u16* wh1 = wpk;             u16* wl1 = wpk + 1179648;
    u16* wh2 = wpk + 2359296;   u16* wl2 = wpk + 3538944;
    u16* wh3 = wpk + 4718592;   u16* wl3 = wpk + 7077888;
    u16* wh4 = wpk + 9437184;   u16* wl4 = wpk + 10027008;
    float* x0f   = (float*)(wsb + 22978560);
    u16*   x2h   = (u16*)(wsb + 22978560);   u16* x2l = x2h + 4194304;
    float* ptsCL = (float*)(wsb + 39755776);
    u16*   x0h   = (u16*)(wsb + 39755776);
    u16*   x0l   = (u16*)(wsb + 48144384);
    u16*   x3h   = x0h;                      u16* x3l = x0l;
    u16*   x1h   = (u16*)(wsb + 56532992);   u16* x1l = x1h + 2097152;
    u16*   wagT  = (u16*)(wsb + 48144384);
    float* wTp   = (float*)(wsb + 48406528);

    pack_wT<<<224, 256, 0, stream>>>(w_off, w_sc, wTp);
    pack_wagT<<<512, 256, 0, stream>>>(w_agg, wagT);
    transpose_pts<<<512, 256, 0, stream>>>(pts_bev, ptsCL);

    transpose_feat<<<1024, 256, 0, stream>>>(feat0, fT0, 32, 88);
    transpose_feat<<< 512, 256, 0, stream>>>(feat1, fT1, 16, 44);
    transpose_feat<<< 128, 256, 0, stream>>>(feat2, fT2,  8, 22);
    transpose_feat<<<  64, 256, 0, stream>>>(feat3, fT3,  4, 11);

    hipMemsetAsync(x0f, 0, (size_t)4194304 * sizeof(float), stream);

    fused_query8<<<NB * NQ / 8, 256, 0, stream>>>(
        ptsCL, l2i, qmask, wTp, b_off, b_sc, wagT, b_agg,
        vox_x, vox_y, vox_z, fT0, x0f);

    // features dead now -> pack conv weights into that region
    pack_conv_w<<<1024, 256, 0, stream>>>(conv1_w, wh1, wl1, 512, 256);
    pack_conv_w<<<1024, 256, 0, stream>>>(conv2_w, wh2, wl2, 256, 512);
    pack_conv_w<<<2048, 256, 0, stream>>>(conv3_w, wh3, wl3, 512, 512);
    pack_conv_w<<< 512, 256, 0, stream>>>(conv4_w, wh4, wl4, 512, 128);

    // wagT/wTp dead now -> x0l may overwrite them
    split_x0<<<4096, 256, 0, stream>>>(x0f, x0h, x0l);

    conv3x3_mfma2<2, 2, false><<<dim3(64, 4), 256, 0, stream>>>(
        x0h, x0l, wh1, wl1, bn1_g, bn1_b, x1h, x1l, nullptr, 512, 256);
    conv3x3_mfma2<2, 2, false><<<dim3(64, 8), 256, 0, stream>>>(
        x1h, x1l, wh2, wl2, bn2_g, bn2_b, x2h, x2l, nullptr, 256, 512);
    conv3x3_mfma2<2, 2, false><<<dim3(64, 8), 256, 0, stream>>>(
        x2h, x2l, wh3, wl3, bn3_g, bn3_b, x3h, x3l, nullptr, 512, 512);
    conv3x3_mfma2<1, 2, true><<<dim3(128, 2), 128, 0, stream>>>(
        x3h, x3l, wh4, wl4, bn4_g, bn4_b, nullptr, nullptr, (float*)d_out, 512, 128);
}